// Round 5
// baseline (5895.839 us; speedup 1.0000x reference)
//
#include <hip/hip_runtime.h>

typedef unsigned int u32;

#define DM 512
#define NH 8
#define DK 64
#define NF 256
#define L_ 8192
#define SCALE 0.35355339059327373f   // 64^-0.25
#define INVSQM 0.0625f               // 256^-0.5
#define EPS_ 1e-6f

__device__ __forceinline__ float bf2f(short s){
  union { u32 u; float f; } x; x.u = ((u32)(unsigned short)s) << 16; return x.f;
}
__device__ __forceinline__ short f2bf(float f){
  union { float f; u32 u; } x; x.f = f;
  u32 r = (x.u + 0x7FFF + ((x.u >> 16) & 1)) >> 16;
  return (short)r;
}

// ---------------- naive tiled GEMM: C[row][col] = sum_k X[row][k] * W[k][col] ----------------
// X: [nrows x 512] fp32 (ABF16=false) or bf16 (ABF16=true); W: [512 x 512] fp32 (NO transpose).
// MODE 0: Out headsplit [(b*8+h)][l][64] bf16;  MODE 1: Out flat [row][512] FP32 (final output).
template<bool ABF16, int MODE>
__global__ __launch_bounds__(256) void k_proj(const void* __restrict__ X, const float* __restrict__ W,
                                              void* __restrict__ Out, int rbase){
  __shared__ float lX[16*64];
  __shared__ float lW[64*16];
  const int t = threadIdx.x, ty = t >> 4, tx = t & 15;
  const int bx = blockIdx.x;
  const int bm = bx >> 5, bn = bx & 31;
  const int row = bm*16 + ty, col = bn*16 + tx;
  float acc = 0.f;
  for (int kb = 0; kb < 8; ++kb){
    #pragma unroll
    for (int i = 0; i < 4; ++i){
      int idx = i*256 + t;
      int r = idx >> 6, c = idx & 63;
      float xv;
      if (ABF16) xv = bf2f(((const short*)X)[(size_t)(rbase + bm*16 + r)*DM + kb*64 + c]);
      else       xv = ((const float*)X)[(size_t)(rbase + bm*16 + r)*DM + kb*64 + c];
      lX[r*64 + c] = xv;
    }
    #pragma unroll
    for (int i = 0; i < 4; ++i){
      int idx = i*256 + t;
      int k = idx >> 4, c = idx & 15;
      lW[k*16 + c] = W[(size_t)(kb*64 + k)*DM + bn*16 + c];
    }
    __syncthreads();
    #pragma unroll
    for (int kk = 0; kk < 64; ++kk)
      acc = fmaf(lX[ty*64 + kk], lW[kk*16 + tx], acc);
    __syncthreads();
  }
  if (MODE == 0){
    int h = col >> 6, dv = col & 63;
    ((short*)Out)[((size_t)((row >> 13)*NH + h)*L_ + (row & 8191))*DK + dv] = f2bf(acc);
  } else {
    ((float*)Out)[(size_t)row*DM + col] = acc;   // FINAL OUTPUT IS FP32
  }
}

// ---------------- per-position stab (max_m proj) and sq (0.0625*|x|^2) ----------------
// grid = nbh*32; block 256; thread = one l.
__global__ __launch_bounds__(256) void k_prep(const short* __restrict__ xh, const float* __restrict__ om,
                                              float* __restrict__ stab, float* __restrict__ sq){
  const int t = threadIdx.x;
  const int bid = blockIdx.x;
  const int bh = bid >> 5, chunk = bid & 31;
  const size_t gl = (size_t)bh*L_ + chunk*256 + t;
  const short* xr_g = xh + gl*DK;
  float xr[64];
  #pragma unroll
  for (int d = 0; d < 64; ++d) xr[d] = bf2f(xr_g[d]);
  float ss = 0.f;
  #pragma unroll
  for (int d = 0; d < 64; ++d) ss = fmaf(xr[d], xr[d], ss);
  float smax = -1e30f;
  for (int m = 0; m < 256; ++m){
    float acc = 0.f;
    #pragma unroll
    for (int d = 0; d < 64; ++d) acc = fmaf(xr[d], om[m*64 + d], acc);
    smax = fmaxf(smax, acc * SCALE);
  }
  stab[gl] = smax;
  sq[gl] = 0.0625f * ss;
}

// ---------------- phi(k) -> kv partials + ksum partials ----------------
// grid = nbh*8 (bh*8+split); block 256 (thread = feature m); each split covers 1024 l's.
__global__ __launch_bounds__(256) void k_phikv(const short* __restrict__ kh, const short* __restrict__ vh,
                                               const float* __restrict__ om,
                                               const float* __restrict__ stabk, const float* __restrict__ sqk,
                                               float* __restrict__ kvp, float* __restrict__ ksp){
  __shared__ short lK[128*64];
  __shared__ short lV[128*64];
  __shared__ float lSt[128], lSq[128];
  const int t = threadIdx.x;
  const int bid = blockIdx.x;
  const int bh = bid >> 3, sp = bid & 7;
  float omr[64];
  #pragma unroll
  for (int d = 0; d < 64; ++d) omr[d] = om[t*64 + d];
  float kvacc[64];
  #pragma unroll
  for (int d = 0; d < 64; ++d) kvacc[d] = 0.f;
  float ks = 0.f;
  for (int c = 0; c < 8; ++c){
    int l0 = sp*1024 + c*128;
    __syncthreads();
    for (int i = 0; i < 32; ++i){
      int idx = i*256 + t;
      lK[idx] = kh[((size_t)bh*L_ + l0)*DK + idx];
      lV[idx] = vh[((size_t)bh*L_ + l0)*DK + idx];
    }
    if (t < 128){
      lSt[t] = stabk[(size_t)bh*L_ + l0 + t];
      lSq[t] = sqk[(size_t)bh*L_ + l0 + t];
    }
    __syncthreads();
    for (int lo = 0; lo < 128; ++lo){
      float acc = 0.f;
      #pragma unroll
      for (int d = 0; d < 64; ++d) acc = fmaf(bf2f(lK[lo*64 + d]), omr[d], acc);
      float e = __expf(acc*SCALE - lSq[lo] - lSt[lo]) * INVSQM + EPS_;
      ks += e;
      #pragma unroll
      for (int d = 0; d < 64; ++d) kvacc[d] = fmaf(e, bf2f(lV[lo*64 + d]), kvacc[d]);
    }
  }
  float* kb = kvp + (size_t)bid*16384 + t*64;
  #pragma unroll
  for (int d = 0; d < 64; ++d) kb[d] = kvacc[d];
  ksp[(size_t)bid*256 + t] = ks;
}

// ---------------- reduce split partials: kv fp32 [bh][256][64], ksum fp32 [bh][256] ----------------
__global__ __launch_bounds__(256) void k_red2(const float* __restrict__ kvp, const float* __restrict__ ksp,
                                              float* __restrict__ kv, float* __restrict__ ksum){
  const int bh = blockIdx.x, t = threadIdx.x;
  for (int i = 0; i < 64; ++i){
    int e = i*256 + t;
    float s = 0.f;
    #pragma unroll
    for (int sp = 0; sp < 8; ++sp) s += kvp[((size_t)bh*8 + sp)*16384 + e];
    kv[(size_t)bh*16384 + e] = s;
  }
  float s2 = 0.f;
  #pragma unroll
  for (int sp = 0; sp < 8; ++sp) s2 += ksp[((size_t)bh*8 + sp)*256 + t];
  ksum[(size_t)bh*256 + t] = s2;
}

// ---------------- phi(q) + num/den -> attn [b*8192+l][512] bf16 ----------------
// grid = nbh*32; block 256; thread = one l.
__global__ __launch_bounds__(256) void k_phiq2(const short* __restrict__ qh, const float* __restrict__ kv,
                                               const float* __restrict__ ksum, const float* __restrict__ om,
                                               const float* __restrict__ stabq, const float* __restrict__ sqq,
                                               short* __restrict__ attn){
  __shared__ float lKv[256*64];   // 64 KB
  __shared__ float lKs[256];
  const int t = threadIdx.x;
  const int bid = blockIdx.x;
  const int bh = bid >> 5, chunk = bid & 31;
  for (int i = 0; i < 64; ++i){
    int idx = i*256 + t;
    lKv[idx] = kv[(size_t)bh*16384 + idx];
  }
  lKs[t] = ksum[(size_t)bh*256 + t];
  __syncthreads();
  const size_t gl = (size_t)bh*L_ + chunk*256 + t;
  const short* qr = qh + gl*DK;
  float xr[64];
  #pragma unroll
  for (int d = 0; d < 64; ++d) xr[d] = bf2f(qr[d]);
  const float stv = stabq[gl], sqv = sqq[gl];
  float num[64];
  #pragma unroll
  for (int d = 0; d < 64; ++d) num[d] = 0.f;
  float den = 0.f;
  for (int m = 0; m < 256; ++m){
    float acc = 0.f;
    #pragma unroll
    for (int d = 0; d < 64; ++d) acc = fmaf(xr[d], om[m*64 + d], acc);
    float e = __expf(acc*SCALE - sqv - stv) * INVSQM + EPS_;
    den = fmaf(e, lKs[m], den);
    #pragma unroll
    for (int dv = 0; dv < 64; ++dv) num[dv] = fmaf(e, lKv[m*64 + dv], num[dv]);
  }
  float rden = 1.0f / (den + EPS_);
  const int b = bh >> 3, h = bh & 7;
  const int l = chunk*256 + t;
  short* ob = attn + ((size_t)b*L_ + l)*DM + h*DK;
  #pragma unroll
  for (int dv = 0; dv < 64; ++dv) ob[dv] = f2bf(num[dv]*rden);
}

extern "C" void kernel_launch(void* const* d_in, const int* in_sizes, int n_in,
                              void* d_out, int out_size, void* d_ws, size_t ws_size,
                              hipStream_t stream){
  const float* Q  = (const float*)d_in[0];
  const float* K  = (const float*)d_in[1];
  const float* V  = (const float*)d_in[2];
  const float* Wq = (const float*)d_in[3];
  const float* Wk = (const float*)d_in[4];
  const float* Wv = (const float*)d_in[5];
  const float* Wo = (const float*)d_in[6];
  const float* Om = (const float*)d_in[7];
  char* ws = (char*)d_ws;

  const size_t MONO_NEED = 124026880ull;   // ~118.3 MB
  if (ws_size >= MONO_NEED){
    short* qh    = (short*)(ws);                    // 33,554,432 B
    short* kh    = (short*)(ws + 33554432);         // 33,554,432 B (attn alias)
    short* vh    = (short*)(ws + 67108864);         // 33,554,432 B
    float* stabq = (float*)(ws + 100663296);        // 1,048,576 B
    float* sqq   = (float*)(ws + 101711872);
    float* stabk = (float*)(ws + 102760448);
    float* sqk   = (float*)(ws + 103809024);
    float* kvp   = (float*)(ws + 104857600);        // 16,777,216 B
    float* ksp   = (float*)(ws + 121634816);        // 262,144 B
    float* kv    = (float*)(ws + 121896960);        // 2,097,152 B
    float* ksum  = (float*)(ws + 123994112);        // 32,768 B
    short* attn  = kh;                              // kh dead after k_phikv

    k_proj<false,0><<<65536, 256, 0, stream>>>(Q, Wq, qh, 0);
    k_proj<false,0><<<65536, 256, 0, stream>>>(K, Wk, kh, 0);
    k_proj<false,0><<<65536, 256, 0, stream>>>(V, Wv, vh, 0);
    k_prep<<<1024, 256, 0, stream>>>(qh, Om, stabq, sqq);
    k_prep<<<1024, 256, 0, stream>>>(kh, Om, stabk, sqk);
    k_phikv<<<256, 256, 0, stream>>>(kh, vh, Om, stabk, sqk, kvp, ksp);
    k_red2<<<32, 256, 0, stream>>>(kvp, ksp, kv, ksum);
    k_phiq2<<<1024, 256, 0, stream>>>(qh, kv, ksum, Om, stabq, sqq, attn);
    k_proj<true,1><<<65536, 256, 0, stream>>>(attn, Wo, d_out, 0);   // fp32 store
  } else {
    // per-batch tier: ~31 MB
    short* qh    = (short*)(ws);                    // 8,388,608 B
    short* kh    = (short*)(ws + 8388608);          // 8,388,608 B (attn alias)
    short* vh    = (short*)(ws + 16777216);         // 8,388,608 B
    float* stabq = (float*)(ws + 25165824);         // 262,144 B
    float* sqq   = (float*)(ws + 25427968);
    float* stabk = (float*)(ws + 25690112);
    float* sqk   = (float*)(ws + 25952256);
    float* kvp   = (float*)(ws + 26214400);         // 4,194,304 B
    float* ksp   = (float*)(ws + 30408704);         // 65,536 B
    float* kv    = (float*)(ws + 30474240);         // 524,288 B
    float* ksum  = (float*)(ws + 30998528);         // 8,192 B
    short* attn  = kh;
    for (int b = 0; b < 4; ++b){
      int rbase = b*L_;
      k_proj<false,0><<<16384, 256, 0, stream>>>(Q, Wq, qh, rbase);
      k_proj<false,0><<<16384, 256, 0, stream>>>(K, Wk, kh, rbase);
      k_proj<false,0><<<16384, 256, 0, stream>>>(V, Wv, vh, rbase);
      k_prep<<<256, 256, 0, stream>>>(qh, Om, stabq, sqq);
      k_prep<<<256, 256, 0, stream>>>(kh, Om, stabk, sqk);
      k_phikv<<<64, 256, 0, stream>>>(kh, vh, Om, stabk, sqk, kvp, ksp);
      k_red2<<<8, 256, 0, stream>>>(kvp, ksp, kv, ksum);
      k_phiq2<<<256, 256, 0, stream>>>(qh, kv, ksum, Om, stabq, sqq, attn);
      k_proj<true,1><<<16384, 256, 0, stream>>>(attn, Wo,
                                                (float*)d_out + (size_t)b*L_*DM, 0);
    }
  }
}

// Round 6
// 361.154 us; speedup vs baseline: 16.3250x; 16.3250x over previous
//
#include <hip/hip_runtime.h>

typedef unsigned int u32;
typedef __attribute__((ext_vector_type(8))) short short8;
typedef __attribute__((ext_vector_type(4))) short short4v;
typedef __attribute__((ext_vector_type(4))) float f32x4;

#define DM 512
#define NH 8
#define DK 64
#define NF 256
#define L_ 8192
#define SCALE 0.35355339059327373f   // 64^-0.25
#define INVSQM 0.0625f               // 256^-0.5
#define EPS_ 1e-6f

__device__ __forceinline__ float bf2f(short s){
  union { u32 u; float f; } x; x.u = ((u32)(unsigned short)s) << 16; return x.f;
}
__device__ __forceinline__ short f2bf(float f){
  union { float f; u32 u; } x; x.f = f;
  u32 r = (x.u + 0x7FFF + ((x.u >> 16) & 1)) >> 16;
  return (short)r;
}

typedef const __attribute__((address_space(1))) u32* gas_t;
typedef __attribute__((address_space(3))) u32* las_t;
__device__ __forceinline__ void gl_lds16(const void* g, void* l){
  __builtin_amdgcn_global_load_lds((gas_t)g, (las_t)l, 16, 0, 0);
}
__device__ __forceinline__ f32x4 mfma16(short8 a, short8 b, f32x4 c){
  return __builtin_amdgcn_mfma_f32_16x16x32_bf16(a, b, c, 0, 0, 0);
}
__device__ __forceinline__ short8 lds_read8(const void* base, int byteoff){
  return *reinterpret_cast<const short8*>((const char*)base + byteoff);
}

// ---------------- transpose 4 fp32 weight matrices -> bf16 Wt[n][k] = W[k][n] ----------------
__global__ __launch_bounds__(256) void k_wt(const float* __restrict__ W0, const float* __restrict__ W1,
                                            const float* __restrict__ W2, const float* __restrict__ W3,
                                            short* __restrict__ Wt){
  int bid = blockIdx.x;              // 4 mats x 64 tiles
  int mat = bid >> 6;
  int tr = (bid >> 3) & 7, tc = bid & 7;
  const float* W = mat==0 ? W0 : mat==1 ? W1 : mat==2 ? W2 : W3;
  short* O = Wt + (size_t)mat*DM*DM;
  __shared__ __align__(16) short tl[64*72];   // rows 144B
  int t = threadIdx.x;
  #pragma unroll
  for (int i=0;i<4;++i){
    int c = i*256 + t;               // 1024 chunks of 4 floats
    int r = c >> 4, cc = c & 15;
    f32x4 v = *reinterpret_cast<const f32x4*>(W + (size_t)(tr*64+r)*DM + tc*64 + cc*4);
    short4v o;
    #pragma unroll
    for (int q=0;q<4;++q) o[q] = f2bf(v[q]);
    *reinterpret_cast<short4v*>((char*)tl + r*144 + cc*8) = o;
  }
  __syncthreads();
  #pragma unroll
  for (int i=0;i<2;++i){
    int c = i*256 + t;
    int n = c >> 3, kc = c & 7;
    short8 v;
    #pragma unroll
    for (int q=0;q<8;++q) v[q] = tl[(kc*8+q)*72 + n];
    *reinterpret_cast<short8*>(O + (size_t)(tc*64+n)*DM + tr*64 + kc*8) = v;
  }
}

// ---------------- omega fp32 -> canonical bf16 ----------------
__global__ __launch_bounds__(256) void k_omc(const float* __restrict__ Om, short* __restrict__ omc){
  int i = blockIdx.x*256 + threadIdx.x;
  f32x4 v = *((const f32x4*)Om + i);
  short4v o;
  #pragma unroll
  for (int q=0;q<4;++q) o[q] = f2bf(v[q]);
  *((short4v*)omc + i) = o;
}

// ---------------- GEMM [rows,512] x Wt[512,512], 128x128 tile, BK=64, LINEAR LDS ----------------
// MODE 0: bf16 headsplit [h][l][64];  MODE 1: FP32 flat [row][512] direct from acc;  MODE 2: bf16 vT [h][dv][L]
template<int MODE, bool AF32>
__global__ __launch_bounds__(256) void k_gemm(const void* __restrict__ A, const short* __restrict__ Bt,
                                              void* __restrict__ Out, int rbase){
  __shared__ __align__(16) short lA[128*64];
  __shared__ __align__(16) short lB[128*64];
  __shared__ __align__(16) short lC[MODE==1 ? 8 : 128*136];
  const int t = threadIdx.x;
  const int w = t >> 6, lane = t & 63;
  const int wr = w >> 1, wc = w & 1;
  const int bx = blockIdx.x;
  const int bm = bx >> 2, bn = bx & 3;
  const int row0 = bm*128, n0 = bn*128;
  f32x4 acc[4][4] = {};
  for (int ks=0; ks<8; ++ks){
    if (AF32){
      const float* gA32 = (const float*)A + (size_t)(rbase+row0)*DM + ks*64;
      #pragma unroll
      for (int rnd=0; rnd<8; ++rnd){
        int c = rnd*256 + t;
        int r = c >> 4, cc = c & 15;
        f32x4 v = *reinterpret_cast<const f32x4*>(gA32 + (size_t)r*DM + cc*4);
        short4v o;
        #pragma unroll
        for (int q=0;q<4;++q) o[q] = f2bf(v[q]);
        *reinterpret_cast<short4v*>((char*)lA + r*128 + cc*8) = o;
      }
    } else {
      const char* gA = (const char*)((const short*)A + (size_t)(rbase+row0)*DM + ks*64);
      #pragma unroll
      for (int rnd=0; rnd<4; ++rnd){
        int d = (rnd*256 + t)*16;
        int r = d >> 7, po = d & 127;
        gl_lds16(gA + (size_t)r*(DM*2) + po, (char*)lA + rnd*4096 + w*1024);
      }
    }
    const char* gB = (const char*)(Bt + (size_t)n0*DM + ks*64);
    #pragma unroll
    for (int rnd=0; rnd<4; ++rnd){
      int d = (rnd*256 + t)*16;
      int r = d >> 7, po = d & 127;
      gl_lds16(gB + (size_t)r*(DM*2) + po, (char*)lB + rnd*4096 + w*1024);
    }
    __syncthreads();
    #pragma unroll
    for (int kk=0; kk<2; ++kk){
      int kb = (kk*32 + ((lane>>4)<<3))*2;
      short8 af[4], bfr[4];
      #pragma unroll
      for (int i=0;i<4;++i){
        int m = wr*64 + i*16 + (lane&15);
        af[i] = lds_read8(lA, m*128 + kb);
      }
      #pragma unroll
      for (int j=0;j<4;++j){
        int n = wc*64 + j*16 + (lane&15);
        bfr[j] = lds_read8(lB, n*128 + kb);
      }
      #pragma unroll
      for (int i=0;i<4;++i)
        #pragma unroll
        for (int j=0;j<4;++j)
          acc[i][j] = mfma16(af[i], bfr[j], acc[i][j]);
    }
    __syncthreads();
  }
  if (MODE == 1){
    // final output: fp32 direct stores from accumulator
    float* Of = (float*)Out;
    #pragma unroll
    for (int i=0;i<4;++i)
      #pragma unroll
      for (int j=0;j<4;++j)
        #pragma unroll
        for (int jj=0;jj<4;++jj){
          int row = wr*64 + i*16 + ((lane>>4)<<2) + jj;
          int col = wc*64 + j*16 + (lane&15);
          Of[(size_t)(row0+row)*DM + n0 + col] = acc[i][j][jj];
        }
    return;
  }
  #pragma unroll
  for (int i=0;i<4;++i)
    #pragma unroll
    for (int j=0;j<4;++j)
      #pragma unroll
      for (int jj=0;jj<4;++jj){
        int row = wr*64 + i*16 + ((lane>>4)<<2) + jj;
        int col = wc*64 + j*16 + (lane&15);
        lC[row*136 + col] = f2bf(acc[i][j][jj]);
      }
  __syncthreads();
  const int b = row0 >> 13;
  const int l0 = row0 & 8191;
  short* Os = (short*)Out;
  if (MODE == 0){
    #pragma unroll
    for (int it=0; it<8; ++it){
      int p = it*256 + t;
      int row = p >> 4, c16 = p & 15;
      short8 v = *reinterpret_cast<const short8*>((char*)lC + row*272 + c16*16);
      int col0 = n0 + c16*8;
      int h = col0 >> 6, dv = col0 & 63;
      size_t off = ((size_t)(b*NH + h)*L_ + (l0+row))*DK + dv;
      *reinterpret_cast<short8*>(Os + off) = v;
    }
  } else {
    #pragma unroll
    for (int it=0; it<8; ++it){
      int p = it*256 + t;
      int col = p >> 4, lp = p & 15;
      short8 v;
      #pragma unroll
      for (int q=0;q<8;++q) v[q] = lC[(lp*8+q)*136 + col];
      int h = (n0+col) >> 6, dv = (n0+col) & 63;
      size_t off = ((size_t)(b*NH+h)*DK + dv)*L_ + l0 + lp*8;
      *reinterpret_cast<short8*>(Os + off) = v;
    }
  }
}

// ---------------- phi(k) + kvT partial + ksum partial (LINEAR LDS) ----------------
// grid = nbh*8 (bh*8+split); 512 threads; each split: 1024 rows = 8 chunks of 128
__global__ __launch_bounds__(512) void k_phik(const short* __restrict__ kh, const short* __restrict__ vT,
                                              const short* __restrict__ omega,
                                              float* __restrict__ kvp, float* __restrict__ ksp){
  __shared__ __align__(16) short lOm[256*64];
  __shared__ __align__(16) short lK[128*64];
  __shared__ __align__(16) short lV[64*128];
  __shared__ __align__(16) short lP[256*136];
  __shared__ float lSq[128];
  __shared__ float lKsP[8][256];
  const int t = threadIdx.x, w = t>>6, lane = t&63;
  const int bid = blockIdx.x;
  const int bh = bid >> 3, sp = bid & 7;
  const char* khb = (const char*)(kh + (size_t)bh*L_*DK);
  const char* vtb = (const char*)(vT + (size_t)bh*DK*L_);
  #pragma unroll
  for (int rnd=0; rnd<4; ++rnd){
    int d = (rnd*512 + t)*16;
    gl_lds16((const char*)omega + d, (char*)lOm + rnd*8192 + w*1024);
  }
  f32x4 kv[4][2] = {};
  float ksa[16] = {};
  for (int c=0;c<8;++c){
    int l0 = sp*1024 + c*128;
    #pragma unroll
    for (int rnd=0; rnd<2; ++rnd){
      int d = (rnd*512 + t)*16;
      gl_lds16(khb + (size_t)l0*128 + d, (char*)lK + rnd*8192 + w*1024);
      { int r = d>>8, po = d&255;
        gl_lds16(vtb + (size_t)r*(L_*2) + (size_t)l0*2 + po, (char*)lV + rnd*8192 + w*1024); }
    }
    __syncthreads();
    {
      int row = t >> 2, part = t & 3;
      float ss = 0.f;
      #pragma unroll
      for (int hh=0; hh<2; ++hh){
        int cb = part*32 + hh*16;
        short8 v = lds_read8(lK, row*128 + cb);
        #pragma unroll
        for (int q=0;q<8;++q){ float f = bf2f(v[q]); ss += f*f; }
      }
      ss += __shfl_xor(ss, 1, 64);
      ss += __shfl_xor(ss, 2, 64);
      if (part==0) lSq[row] = 0.0625f * ss;
    }
    __syncthreads();
    f32x4 p[16] = {};
    #pragma unroll
    for (int kk=0;kk<2;++kk){
      int kb = (kk*32 + ((lane>>4)<<3))*2;
      int m = w*16 + (lane&15);
      short8 a = lds_read8(lK, m*128 + kb);
      #pragma unroll
      for (int ft=0; ft<16; ++ft){
        int n = ft*16 + (lane&15);
        short8 b = lds_read8(lOm, n*128 + kb);
        p[ft] = mfma16(a, b, p[ft]);
      }
    }
    float mj[4] = {-1e30f,-1e30f,-1e30f,-1e30f};
    #pragma unroll
    for (int ft=0; ft<16; ++ft)
      #pragma unroll
      for (int j=0;j<4;++j){ float pv = p[ft][j]*SCALE; p[ft][j]=pv; mj[j] = fmaxf(mj[j], pv); }
    #pragma unroll
    for (int j=0;j<4;++j){
      float v = mj[j];
      v = fmaxf(v, __shfl_xor(v,1,64)); v = fmaxf(v, __shfl_xor(v,2,64));
      v = fmaxf(v, __shfl_xor(v,4,64)); v = fmaxf(v, __shfl_xor(v,8,64));
      mj[j] = v;
    }
    float sqv[4];
    #pragma unroll
    for (int j=0;j<4;++j) sqv[j] = lSq[w*16 + ((lane>>4)<<2) + j];
    int llb = w*16 + ((lane>>4)<<2);
    #pragma unroll
    for (int ft=0; ft<16; ++ft){
      float sum = 0.f;
      int feat = ft*16 + (lane&15);
      #pragma unroll
      for (int j=0;j<4;++j){
        float e = __expf(p[ft][j] - sqv[j] - mj[j]) * INVSQM + EPS_;
        sum += e;
        lP[feat*136 + llb + j] = f2bf(e);
      }
      ksa[ft] += sum;
    }
    __syncthreads();
    #pragma unroll
    for (int ks2=0; ks2<4; ++ks2){
      int kb = (ks2*32 + ((lane>>4)<<3))*2;
      short8 a[4], b[2];
      #pragma unroll
      for (int i=0;i<4;++i){
        int m = i*16 + (lane&15);
        a[i] = lds_read8(lV, m*256 + kb);
      }
      #pragma unroll
      for (int j=0;j<2;++j){
        int n = (2*w+j)*16 + (lane&15);
        b[j] = lds_read8(lP, n*272 + kb);
      }
      #pragma unroll
      for (int i=0;i<4;++i)
        #pragma unroll
        for (int j=0;j<2;++j)
          kv[i][j] = mfma16(a[i], b[j], kv[i][j]);
    }
    __syncthreads();
  }
  float* kvb = kvp + (size_t)bid*64*256;
  #pragma unroll
  for (int i=0;i<4;++i)
    #pragma unroll
    for (int j=0;j<2;++j)
      #pragma unroll
      for (int jj=0;jj<4;++jj){
        int dv = i*16 + ((lane>>4)<<2) + jj;
        int feat = (2*w+j)*16 + (lane&15);
        kvb[dv*256 + feat] = kv[i][j][jj];
      }
  #pragma unroll
  for (int ft=0; ft<16; ++ft){
    float v = ksa[ft];
    v += __shfl_xor(v, 16, 64);
    v += __shfl_xor(v, 32, 64);
    if (lane < 16) lKsP[w][ft*16 + lane] = v;
  }
  __syncthreads();
  if (t < 256){
    float s = 0.f;
    #pragma unroll
    for (int wv=0; wv<8; ++wv) s += lKsP[wv][t];
    ksp[(size_t)bid*256 + t] = s;
  }
}

// ---------------- reduce kv partials -> kvT bf16, ksum fp32 ----------------
__global__ __launch_bounds__(256) void k_red(const float* __restrict__ kvp, const float* __restrict__ ksp,
                                             short* __restrict__ kvb, float* __restrict__ ksum){
  int bid = blockIdx.x;
  int bh = bid >> 3, part = bid & 7;
  int t = threadIdx.x;
  const float* base = kvp + (size_t)bh*8*16384;
  short* ob = kvb + (size_t)bh*16384;
  for (int i=0;i<8;++i){
    int e = part*2048 + i*256 + t;
    float s = 0.f;
    #pragma unroll
    for (int sp2=0; sp2<8; ++sp2) s += base[(size_t)sp2*16384 + e];
    ob[e] = f2bf(s);
  }
  if (part == 0){
    const float* kb = ksp + (size_t)bh*8*256;
    float s2 = 0.f;
    #pragma unroll
    for (int sp2=0; sp2<8; ++sp2) s2 += kb[sp2*256 + t];
    ksum[bh*256 + t] = s2;
  }
}

// ---------------- phi(q) + num/den -> attn [b][l][512] (LINEAR LDS) ----------------
// grid = nbh*64 (bh*64 + ltile); 512 threads; 128 rows per block
__global__ __launch_bounds__(512) void k_phiq(const short* __restrict__ qh, const short* __restrict__ kvb,
                                              const float* __restrict__ ksum, const short* __restrict__ omega,
                                              short* __restrict__ attn){
  __shared__ __align__(16) short lOm[256*64];
  __shared__ __align__(16) short lQ[128*64];
  __shared__ __align__(16) short lKv[64*256];
  __shared__ __align__(16) short lP[128*264];
  __shared__ float lSq[128];
  __shared__ float lKs[256];
  __shared__ float lDen[128];
  const int t = threadIdx.x, w = t>>6, lane = t&63;
  const int bid = blockIdx.x;
  const int bh = bid >> 6, lt = bid & 63;
  const int l0 = lt*128;
  const char* qb = (const char*)(qh + (size_t)bh*L_*DK);
  #pragma unroll
  for (int rnd=0; rnd<4; ++rnd){
    int d = (rnd*512 + t)*16;
    gl_lds16((const char*)omega + d, (char*)lOm + rnd*8192 + w*1024);
  }
  #pragma unroll
  for (int rnd=0; rnd<2; ++rnd){
    int d = (rnd*512 + t)*16;
    gl_lds16(qb + (size_t)l0*128 + d, (char*)lQ + rnd*8192 + w*1024);
  }
  const char* kvg = (const char*)(kvb + (size_t)bh*16384);
  #pragma unroll
  for (int rnd=0; rnd<4; ++rnd){
    int d = (rnd*512 + t)*16;
    gl_lds16(kvg + d, (char*)lKv + rnd*8192 + w*1024);
  }
  if (t < 256) lKs[t] = ksum[bh*256 + t];
  __syncthreads();
  {
    int row = t >> 2, part = t & 3;
    float ss = 0.f;
    #pragma unroll
    for (int hh=0; hh<2; ++hh){
      int cb = part*32 + hh*16;
      short8 v = lds_read8(lQ, row*128 + cb);
      #pragma unroll
      for (int q=0;q<8;++q){ float f = bf2f(v[q]); ss += f*f; }
    }
    ss += __shfl_xor(ss, 1, 64);
    ss += __shfl_xor(ss, 2, 64);
    if (part==0) lSq[row] = 0.0625f * ss;
  }
  __syncthreads();
  f32x4 p[16] = {};
  #pragma unroll
  for (int kk=0;kk<2;++kk){
    int kb = (kk*32 + ((lane>>4)<<3))*2;
    int m = w*16 + (lane&15);
    short8 a = lds_read8(lQ, m*128 + kb);
    #pragma unroll
    for (int ft=0; ft<16; ++ft){
      int n = ft*16 + (lane&15);
      short8 b = lds_read8(lOm, n*128 + kb);
      p[ft] = mfma16(a, b, p[ft]);
    }
  }
  float mj[4] = {-1e30f,-1e30f,-1e30f,-1e30f};
  #pragma unroll
  for (int ft=0;ft<16;++ft)
    #pragma unroll
    for (int j=0;j<4;++j){ float pv = p[ft][j]*SCALE; p[ft][j]=pv; mj[j]=fmaxf(mj[j],pv); }
  #pragma unroll
  for (int j=0;j<4;++j){
    float v = mj[j];
    v = fmaxf(v,__shfl_xor(v,1,64)); v = fmaxf(v,__shfl_xor(v,2,64));
    v = fmaxf(v,__shfl_xor(v,4,64)); v = fmaxf(v,__shfl_xor(v,8,64));
    mj[j] = v;
  }
  float sqv[4];
  #pragma unroll
  for (int j=0;j<4;++j) sqv[j] = lSq[w*16 + ((lane>>4)<<2) + j];
  float dpart[4] = {0.f,0.f,0.f,0.f};
  int rb = w*16 + ((lane>>4)<<2);
  #pragma unroll
  for (int ft=0;ft<16;++ft){
    int feat = ft*16 + (lane&15);
    float ksf = lKs[feat];
    #pragma unroll
    for (int j=0;j<4;++j){
      float e = __expf(p[ft][j]-sqv[j]-mj[j])*INVSQM + EPS_;
      dpart[j] += e*ksf;
      lP[(rb+j)*264 + feat] = f2bf(e);
    }
  }
  #pragma unroll
  for (int j=0;j<4;++j){
    float v = dpart[j];
    v += __shfl_xor(v,1,64); v += __shfl_xor(v,2,64);
    v += __shfl_xor(v,4,64); v += __shfl_xor(v,8,64);
    if ((lane&15)==0) lDen[rb + j] = v;
  }
  __syncthreads();
  f32x4 nc[4] = {};
  #pragma unroll
  for (int ks2=0; ks2<8; ++ks2){
    int kb = (ks2*32 + ((lane>>4)<<3))*2;
    int n = w*16 + (lane&15);
    short8 bfr = lds_read8(lP, n*528 + kb);
    #pragma unroll
    for (int i=0;i<4;++i){
      int m = i*16 + (lane&15);
      short8 a = lds_read8(lKv, m*512 + kb);
      nc[i] = mfma16(a, bfr, nc[i]);
    }
  }
  const int b = bh >> 3, h = bh & 7;
  const int l = w*16 + (lane&15);
  float rden = 1.0f / (lDen[l] + EPS_);
  #pragma unroll
  for (int i=0;i<4;++i){
    short4v ov;
    #pragma unroll
    for (int jj=0;jj<4;++jj) ov[jj] = f2bf(nc[i][jj]*rden);
    size_t off = ((size_t)(b*L_ + l0 + l))*DM + h*DK + i*16 + ((lane>>4)<<2);
    *reinterpret_cast<short4v*>(attn + off) = ov;
  }
}

extern "C" void kernel_launch(void* const* d_in, const int* in_sizes, int n_in,
                              void* d_out, int out_size, void* d_ws, size_t ws_size,
                              hipStream_t stream){
  const float* Q  = (const float*)d_in[0];
  const float* K  = (const float*)d_in[1];
  const float* V  = (const float*)d_in[2];
  const float* Wq = (const float*)d_in[3];
  const float* Wk = (const float*)d_in[4];
  const float* Wv = (const float*)d_in[5];
  const float* Wo = (const float*)d_in[6];
  const float* Om = (const float*)d_in[7];
  char* ws = (char*)d_ws;

  short* wt  = (short*)(ws);                  // 2 MB (4 transposed 512x512 bf16)
  short* omc = (short*)(ws + 2097152);        // 64 KB slot

  k_wt<<<256, 256, 0, stream>>>(Wq, Wk, Wv, Wo, wt);
  k_omc<<<16, 256, 0, stream>>>(Om, omc);

  const size_t MONO_NEED = 120946688ull;      // ~115.3 MB
  if (ws_size >= MONO_NEED){
    short* qh   = (short*)(ws + 2162688);
    short* kh   = (short*)(ws + 35717120);
    short* vT   = (short*)(ws + 69271552);
    float* kvp  = (float*)(ws + 102825984);
    float* ksp  = (float*)(ws + 119603200);
    short* kvb  = (short*)(ws + 119865344);
    float* ksum = (float*)(ws + 120913920);
    short* attn = kh;                         // kh dead after k_phik
    k_gemm<0,true ><<<1024, 256, 0, stream>>>(Q, wt,          qh, 0);
    k_gemm<0,true ><<<1024, 256, 0, stream>>>(K, wt + 262144, kh, 0);
    k_gemm<2,true ><<<1024, 256, 0, stream>>>(V, wt + 524288, vT, 0);
    k_phik<<<256, 512, 0, stream>>>(kh, vT, omc, kvp, ksp);
    k_red<<<256, 256, 0, stream>>>(kvp, ksp, kvb, ksum);
    k_phiq<<<2048, 512, 0, stream>>>(qh, kvb, ksum, omc, attn);
    k_gemm<1,false><<<1024, 256, 0, stream>>>(attn, wt + 786432, d_out, 0);
  } else {
    // per-batch tier: ~30.4 MB of workspace
    short* qh   = (short*)(ws + 2162688);
    short* kh   = (short*)(ws + 10551296);
    short* vT   = (short*)(ws + 18939904);
    float* kvp  = (float*)(ws + 27328512);
    float* ksp  = (float*)(ws + 31522816);
    short* kvb  = (short*)(ws + 31588352);
    float* ksum = (float*)(ws + 31850496);
    short* attn = kh;
    for (int b=0; b<4; ++b){
      int rbase = b*8192;
      k_gemm<0,true ><<<256, 256, 0, stream>>>(Q, wt,          qh, rbase);
      k_gemm<0,true ><<<256, 256, 0, stream>>>(K, wt + 262144, kh, rbase);
      k_gemm<2,true ><<<256, 256, 0, stream>>>(V, wt + 524288, vT, rbase);
      k_phik<<<64, 512, 0, stream>>>(kh, vT, omc, kvp, ksp);
      k_red<<<64, 256, 0, stream>>>(kvp, ksp, kvb, ksum);
      k_phiq<<<512, 512, 0, stream>>>(qh, kvb, ksum, omc, attn);
      k_gemm<1,false><<<256, 256, 0, stream>>>(attn, wt + 786432,
                                               (float*)d_out + (size_t)b*8192*DM, 0);
    }
  }
}

// Round 7
// 344.980 us; speedup vs baseline: 17.0904x; 1.0469x over previous
//
#include <hip/hip_runtime.h>

typedef unsigned int u32;
typedef __attribute__((ext_vector_type(8))) short short8;
typedef __attribute__((ext_vector_type(4))) short short4v;
typedef __attribute__((ext_vector_type(4))) float f32x4;

#define DM 512
#define NH 8
#define DK 64
#define NF 256
#define L_ 8192
#define SCALE 0.35355339059327373f   // 64^-0.25
#define INVSQM 0.0625f               // 256^-0.5
#define EPS_ 1e-6f

__device__ __forceinline__ float bf2f(short s){
  union { u32 u; float f; } x; x.u = ((u32)(unsigned short)s) << 16; return x.f;
}
__device__ __forceinline__ short f2bf(float f){
  union { float f; u32 u; } x; x.f = f;
  u32 r = (x.u + 0x7FFF + ((x.u >> 16) & 1)) >> 16;
  return (short)r;
}

typedef const __attribute__((address_space(1))) u32* gas_t;
typedef __attribute__((address_space(3))) u32* las_t;
__device__ __forceinline__ void gl_lds16(const void* g, void* l){
  __builtin_amdgcn_global_load_lds((gas_t)g, (las_t)l, 16, 0, 0);
}
__device__ __forceinline__ f32x4 mfma16(short8 a, short8 b, f32x4 c){
  return __builtin_amdgcn_mfma_f32_16x16x32_bf16(a, b, c, 0, 0, 0);
}
__device__ __forceinline__ short8 lds_read8(const void* base, int byteoff){
  return *reinterpret_cast<const short8*>((const char*)base + byteoff);
}

// ---------------- transpose 4 fp32 weight matrices -> bf16 Wt[n][k] = W[k][n] ----------------
__global__ __launch_bounds__(256) void k_wt(const float* __restrict__ W0, const float* __restrict__ W1,
                                            const float* __restrict__ W2, const float* __restrict__ W3,
                                            short* __restrict__ Wt){
  int bid = blockIdx.x;              // 4 mats x 64 tiles
  int mat = bid >> 6;
  int tr = (bid >> 3) & 7, tc = bid & 7;
  const float* W = mat==0 ? W0 : mat==1 ? W1 : mat==2 ? W2 : W3;
  short* O = Wt + (size_t)mat*DM*DM;
  __shared__ __align__(16) short tl[64*72];   // rows 144B
  int t = threadIdx.x;
  #pragma unroll
  for (int i=0;i<4;++i){
    int c = i*256 + t;               // 1024 chunks of 4 floats
    int r = c >> 4, cc = c & 15;
    f32x4 v = *reinterpret_cast<const f32x4*>(W + (size_t)(tr*64+r)*DM + tc*64 + cc*4);
    short4v o;
    #pragma unroll
    for (int q=0;q<4;++q) o[q] = f2bf(v[q]);
    *reinterpret_cast<short4v*>((char*)tl + r*144 + cc*8) = o;
  }
  __syncthreads();
  #pragma unroll
  for (int i=0;i<2;++i){
    int c = i*256 + t;
    int n = c >> 3, kc = c & 7;
    short8 v;
    #pragma unroll
    for (int q=0;q<8;++q) v[q] = tl[(kc*8+q)*72 + n];
    *reinterpret_cast<short8*>(O + (size_t)(tc*64+n)*DM + tr*64 + kc*8) = v;
  }
}

// ---------------- omega fp32 -> canonical bf16 ----------------
__global__ __launch_bounds__(256) void k_omc(const float* __restrict__ Om, short* __restrict__ omc){
  int i = blockIdx.x*256 + threadIdx.x;
  f32x4 v = *((const f32x4*)Om + i);
  short4v o;
  #pragma unroll
  for (int q=0;q<4;++q) o[q] = f2bf(v[q]);
  *((short4v*)omc + i) = o;
}

// ---------------- GEMM [rows,512] x Wt[512,512], 128x128 tile, BK=64, LINEAR LDS ----------------
// MODE 0: bf16 headsplit [h][l][64];  MODE 1: FP32 flat [row][512] direct from acc;  MODE 2: bf16 vT [h][dv][L]
template<int MODE, bool AF32>
__global__ __launch_bounds__(256) void k_gemm(const void* __restrict__ A, const short* __restrict__ Bt,
                                              void* __restrict__ Out, int rbase){
  __shared__ __align__(16) short lA[128*64];
  __shared__ __align__(16) short lB[128*64];
  __shared__ __align__(16) short lC[MODE==1 ? 8 : 128*136];
  const int t = threadIdx.x;
  const int w = t >> 6, lane = t & 63;
  const int wr = w >> 1, wc = w & 1;
  const int bx = blockIdx.x;
  const int bm = bx >> 2, bn = bx & 3;
  const int row0 = bm*128, n0 = bn*128;
  f32x4 acc[4][4] = {};
  for (int ks=0; ks<8; ++ks){
    if (AF32){
      const float* gA32 = (const float*)A + (size_t)(rbase+row0)*DM + ks*64;
      #pragma unroll
      for (int rnd=0; rnd<8; ++rnd){
        int c = rnd*256 + t;
        int r = c >> 4, cc = c & 15;
        f32x4 v = *reinterpret_cast<const f32x4*>(gA32 + (size_t)r*DM + cc*4);
        short4v o;
        #pragma unroll
        for (int q=0;q<4;++q) o[q] = f2bf(v[q]);
        *reinterpret_cast<short4v*>((char*)lA + r*128 + cc*8) = o;
      }
    } else {
      const char* gA = (const char*)((const short*)A + (size_t)(rbase+row0)*DM + ks*64);
      #pragma unroll
      for (int rnd=0; rnd<4; ++rnd){
        int d = (rnd*256 + t)*16;
        int r = d >> 7, po = d & 127;
        gl_lds16(gA + (size_t)r*(DM*2) + po, (char*)lA + rnd*4096 + w*1024);
      }
    }
    const char* gB = (const char*)(Bt + (size_t)n0*DM + ks*64);
    #pragma unroll
    for (int rnd=0; rnd<4; ++rnd){
      int d = (rnd*256 + t)*16;
      int r = d >> 7, po = d & 127;
      gl_lds16(gB + (size_t)r*(DM*2) + po, (char*)lB + rnd*4096 + w*1024);
    }
    __syncthreads();
    #pragma unroll
    for (int kk=0; kk<2; ++kk){
      int kb = (kk*32 + ((lane>>4)<<3))*2;
      short8 af[4], bfr[4];
      #pragma unroll
      for (int i=0;i<4;++i){
        int m = wr*64 + i*16 + (lane&15);
        af[i] = lds_read8(lA, m*128 + kb);
      }
      #pragma unroll
      for (int j=0;j<4;++j){
        int n = wc*64 + j*16 + (lane&15);
        bfr[j] = lds_read8(lB, n*128 + kb);
      }
      #pragma unroll
      for (int i=0;i<4;++i)
        #pragma unroll
        for (int j=0;j<4;++j)
          acc[i][j] = mfma16(af[i], bfr[j], acc[i][j]);
    }
    __syncthreads();
  }
  if (MODE == 1){
    float* Of = (float*)Out;
    #pragma unroll
    for (int i=0;i<4;++i)
      #pragma unroll
      for (int j=0;j<4;++j)
        #pragma unroll
        for (int jj=0;jj<4;++jj){
          int row = wr*64 + i*16 + ((lane>>4)<<2) + jj;
          int col = wc*64 + j*16 + (lane&15);
          Of[(size_t)(row0+row)*DM + n0 + col] = acc[i][j][jj];
        }
    return;
  }
  #pragma unroll
  for (int i=0;i<4;++i)
    #pragma unroll
    for (int j=0;j<4;++j)
      #pragma unroll
      for (int jj=0;jj<4;++jj){
        int row = wr*64 + i*16 + ((lane>>4)<<2) + jj;
        int col = wc*64 + j*16 + (lane&15);
        lC[row*136 + col] = f2bf(acc[i][j][jj]);
      }
  __syncthreads();
  const int b = row0 >> 13;
  const int l0 = row0 & 8191;
  short* Os = (short*)Out;
  if (MODE == 0){
    #pragma unroll
    for (int it=0; it<8; ++it){
      int p = it*256 + t;
      int row = p >> 4, c16 = p & 15;
      short8 v = *reinterpret_cast<const short8*>((char*)lC + row*272 + c16*16);
      int col0 = n0 + c16*8;
      int h = col0 >> 6, dv = col0 & 63;
      size_t off = ((size_t)(b*NH + h)*L_ + (l0+row))*DK + dv;
      *reinterpret_cast<short8*>(Os + off) = v;
    }
  } else {
    #pragma unroll
    for (int it=0; it<8; ++it){
      int p = it*256 + t;
      int col = p >> 4, lp = p & 15;
      short8 v;
      #pragma unroll
      for (int q=0;q<8;++q) v[q] = lC[(lp*8+q)*136 + col];
      int h = (n0+col) >> 6, dv = (n0+col) & 63;
      size_t off = ((size_t)(b*NH+h)*DK + dv)*L_ + l0 + lp*8;
      *reinterpret_cast<short8*>(Os + off) = v;
    }
  }
}

// ---------------- phi(k) + kvT partial + ksum partial (LINEAR LDS) ----------------
// grid = nbh*8 (bh*8+split); 512 threads; each split: 1024 rows = 8 chunks of 128
__global__ __launch_bounds__(512) void k_phik(const short* __restrict__ kh, const short* __restrict__ vT,
                                              const short* __restrict__ omega,
                                              float* __restrict__ kvp, float* __restrict__ ksp){
  __shared__ __align__(16) short lOm[256*64];
  __shared__ __align__(16) short lK[128*64];
  __shared__ __align__(16) short lV[64*128];
  __shared__ __align__(16) short lP[256*136];
  __shared__ float lSq[128];
  __shared__ float lKsP[8][256];
  const int t = threadIdx.x, w = t>>6, lane = t&63;
  const int bid = blockIdx.x;
  const int bh = bid >> 3, sp = bid & 7;
  const char* khb = (const char*)(kh + (size_t)bh*L_*DK);
  const char* vtb = (const char*)(vT + (size_t)bh*DK*L_);
  #pragma unroll
  for (int rnd=0; rnd<4; ++rnd){
    int d = (rnd*512 + t)*16;
    gl_lds16((const char*)omega + d, (char*)lOm + rnd*8192 + w*1024);
  }
  f32x4 kv[4][2] = {};
  float ksa[16] = {};
  for (int c=0;c<8;++c){
    int l0 = sp*1024 + c*128;
    #pragma unroll
    for (int rnd=0; rnd<2; ++rnd){
      int d = (rnd*512 + t)*16;
      gl_lds16(khb + (size_t)l0*128 + d, (char*)lK + rnd*8192 + w*1024);
      { int r = d>>8, po = d&255;
        gl_lds16(vtb + (size_t)r*(L_*2) + (size_t)l0*2 + po, (char*)lV + rnd*8192 + w*1024); }
    }
    __syncthreads();
    {
      int row = t >> 2, part = t & 3;
      float ss = 0.f;
      #pragma unroll
      for (int hh=0; hh<2; ++hh){
        int cb = part*32 + hh*16;
        short8 v = lds_read8(lK, row*128 + cb);
        #pragma unroll
        for (int q=0;q<8;++q){ float f = bf2f(v[q]); ss += f*f; }
      }
      ss += __shfl_xor(ss, 1, 64);
      ss += __shfl_xor(ss, 2, 64);
      if (part==0) lSq[row] = 0.0625f * ss;
    }
    __syncthreads();
    f32x4 p[16] = {};
    #pragma unroll
    for (int kk=0;kk<2;++kk){
      int kb = (kk*32 + ((lane>>4)<<3))*2;
      int m = w*16 + (lane&15);
      short8 a = lds_read8(lK, m*128 + kb);
      #pragma unroll
      for (int ft=0; ft<16; ++ft){
        int n = ft*16 + (lane&15);
        short8 b = lds_read8(lOm, n*128 + kb);
        p[ft] = mfma16(a, b, p[ft]);
      }
    }
    float mj[4] = {-1e30f,-1e30f,-1e30f,-1e30f};
    #pragma unroll
    for (int ft=0; ft<16; ++ft)
      #pragma unroll
      for (int j=0;j<4;++j){ float pv = p[ft][j]*SCALE; p[ft][j]=pv; mj[j] = fmaxf(mj[j], pv); }
    #pragma unroll
    for (int j=0;j<4;++j){
      float v = mj[j];
      v = fmaxf(v, __shfl_xor(v,1,64)); v = fmaxf(v, __shfl_xor(v,2,64));
      v = fmaxf(v, __shfl_xor(v,4,64)); v = fmaxf(v, __shfl_xor(v,8,64));
      mj[j] = v;
    }
    float sqv[4];
    #pragma unroll
    for (int j=0;j<4;++j) sqv[j] = lSq[w*16 + ((lane>>4)<<2) + j];
    int llb = w*16 + ((lane>>4)<<2);
    #pragma unroll
    for (int ft=0; ft<16; ++ft){
      float sum = 0.f;
      int feat = ft*16 + (lane&15);
      #pragma unroll
      for (int j=0;j<4;++j){
        float e = __expf(p[ft][j] - sqv[j] - mj[j]) * INVSQM + EPS_;
        sum += e;
        lP[feat*136 + llb + j] = f2bf(e);
      }
      ksa[ft] += sum;
    }
    __syncthreads();
    #pragma unroll
    for (int ks2=0; ks2<4; ++ks2){
      int kb = (ks2*32 + ((lane>>4)<<3))*2;
      short8 a[4], b[2];
      #pragma unroll
      for (int i=0;i<4;++i){
        int m = i*16 + (lane&15);
        a[i] = lds_read8(lV, m*256 + kb);
      }
      #pragma unroll
      for (int j=0;j<2;++j){
        int n = (2*w+j)*16 + (lane&15);
        b[j] = lds_read8(lP, n*272 + kb);
      }
      #pragma unroll
      for (int i=0;i<4;++i)
        #pragma unroll
        for (int j=0;j<2;++j)
          kv[i][j] = mfma16(a[i], b[j], kv[i][j]);
    }
    __syncthreads();
  }
  float* kvb = kvp + (size_t)bid*64*256;
  #pragma unroll
  for (int i=0;i<4;++i)
    #pragma unroll
    for (int j=0;j<2;++j)
      #pragma unroll
      for (int jj=0;jj<4;++jj){
        int dv = i*16 + ((lane>>4)<<2) + jj;
        int feat = (2*w+j)*16 + (lane&15);
        kvb[dv*256 + feat] = kv[i][j][jj];
      }
  #pragma unroll
  for (int ft=0; ft<16; ++ft){
    float v = ksa[ft];
    v += __shfl_xor(v, 16, 64);
    v += __shfl_xor(v, 32, 64);
    if (lane < 16) lKsP[w][ft*16 + lane] = v;
  }
  __syncthreads();
  if (t < 256){
    float s = 0.f;
    #pragma unroll
    for (int wv=0; wv<8; ++wv) s += lKsP[wv][t];
    ksp[(size_t)bid*256 + t] = s;
  }
}

// ---------------- reduce kv partials -> kvT bf16, ksum fp32 ----------------
__global__ __launch_bounds__(256) void k_red(const float* __restrict__ kvp, const float* __restrict__ ksp,
                                             short* __restrict__ kvb, float* __restrict__ ksum){
  int bid = blockIdx.x;
  int bh = bid >> 3, part = bid & 7;
  int t = threadIdx.x;
  const float* base = kvp + (size_t)bh*8*16384;
  short* ob = kvb + (size_t)bh*16384;
  for (int i=0;i<8;++i){
    int e = part*2048 + i*256 + t;
    float s = 0.f;
    #pragma unroll
    for (int sp2=0; sp2<8; ++sp2) s += base[(size_t)sp2*16384 + e];
    ob[e] = f2bf(s);
  }
  if (part == 0){
    const float* kb = ksp + (size_t)bh*8*256;
    float s2 = 0.f;
    #pragma unroll
    for (int sp2=0; sp2<8; ++sp2) s2 += kb[sp2*256 + t];
    ksum[bh*256 + t] = s2;
  }
}

// ---------------- phi(q) + num/den -> attn [b][l][512] — 68KB LDS, 2 blocks/CU ----------------
// grid = nbh*64 (bh*64 + ltile); 512 threads; 128 rows per block.
// bufA: omega [256][64] during proj, then kvT [64][256] during PV (aliased).
// bufB: Q [128][64] during proj, then P [128][136] (feature-half, two PV passes; wave-private rows).
__global__ __launch_bounds__(512, 4) void k_phiq(const short* __restrict__ qh, const short* __restrict__ kvb,
                                                 const float* __restrict__ ksum, const short* __restrict__ omega,
                                                 short* __restrict__ attn){
  __shared__ __align__(16) char smem[69632];
  short* bufA = (short*)smem;                  // 32768 B
  short* bufB = (short*)(smem + 32768);        // 34816 B (128 rows x 272B)
  float* lSq  = (float*)(smem + 67584);        // 512 B
  float* lKs  = (float*)(smem + 68096);        // 1024 B
  float* lDen = (float*)(smem + 69120);        // 512 B
  const int t = threadIdx.x, w = t>>6, lane = t&63;
  const int bid = blockIdx.x;
  const int bh = bid >> 6, lt = bid & 63;
  const int l0 = lt*128;
  const char* qb = (const char*)(qh + (size_t)bh*L_*DK);
  #pragma unroll
  for (int rnd=0; rnd<4; ++rnd){
    int d = (rnd*512 + t)*16;
    gl_lds16((const char*)omega + d, (char*)bufA + rnd*8192 + w*1024);
  }
  #pragma unroll
  for (int rnd=0; rnd<2; ++rnd){
    int d = (rnd*512 + t)*16;
    gl_lds16(qb + (size_t)l0*128 + d, (char*)bufB + rnd*8192 + w*1024);
  }
  if (t < 256) lKs[t] = ksum[bh*256 + t];
  __syncthreads();
  { // sq = 0.0625*|q|^2 per row (reads bufB = Q)
    int row = t >> 2, part = t & 3;
    float ss = 0.f;
    #pragma unroll
    for (int hh=0; hh<2; ++hh){
      int cb = part*32 + hh*16;
      short8 v = lds_read8(bufB, row*128 + cb);
      #pragma unroll
      for (int q=0;q<8;++q){ float f = bf2f(v[q]); ss += f*f; }
    }
    ss += __shfl_xor(ss, 1, 64);
    ss += __shfl_xor(ss, 2, 64);
    if (part==0) lSq[row] = 0.0625f * ss;
  }
  __syncthreads();
  // proj MFMA: A = Q rows (bufB), B = omega rows (bufA)
  f32x4 p[16] = {};
  #pragma unroll
  for (int kk=0;kk<2;++kk){
    int kb = (kk*32 + ((lane>>4)<<3))*2;
    int m = w*16 + (lane&15);
    short8 a = lds_read8(bufB, m*128 + kb);
    #pragma unroll
    for (int ft=0; ft<16; ++ft){
      int n = ft*16 + (lane&15);
      short8 b = lds_read8(bufA, n*128 + kb);
      p[ft] = mfma16(a, b, p[ft]);
    }
  }
  float mj[4] = {-1e30f,-1e30f,-1e30f,-1e30f};
  #pragma unroll
  for (int ft=0;ft<16;++ft)
    #pragma unroll
    for (int j=0;j<4;++j){ float pv = p[ft][j]*SCALE; p[ft][j]=pv; mj[j]=fmaxf(mj[j],pv); }
  #pragma unroll
  for (int j=0;j<4;++j){
    float v = mj[j];
    v = fmaxf(v,__shfl_xor(v,1,64)); v = fmaxf(v,__shfl_xor(v,2,64));
    v = fmaxf(v,__shfl_xor(v,4,64)); v = fmaxf(v,__shfl_xor(v,8,64));
    mj[j] = v;
  }
  float sqv[4];
  #pragma unroll
  for (int j=0;j<4;++j) sqv[j] = lSq[w*16 + ((lane>>4)<<2) + j];
  __syncthreads();   // all waves done reading omega (bufA) and Q (bufB)
  // stage kvT [64][256] into bufA; latency hides under exp pass 1
  const char* kvg = (const char*)(kvb + (size_t)bh*16384);
  #pragma unroll
  for (int rnd=0; rnd<4; ++rnd){
    int d = (rnd*512 + t)*16;
    gl_lds16(kvg + d, (char*)bufA + rnd*8192 + w*1024);
  }
  float dpart[4] = {0.f,0.f,0.f,0.f};
  const int rb = w*16 + ((lane>>4)<<2);
  #pragma unroll
  for (int ft=0;ft<8;++ft){   // pass 1: features 0..127 -> bufB (P), wave-private rows
    int feat = ft*16 + (lane&15);
    float ksf = lKs[feat];
    #pragma unroll
    for (int j=0;j<4;++j){
      float e = __expf(p[ft][j]-sqv[j]-mj[j])*INVSQM + EPS_;
      dpart[j] += e*ksf;
      bufB[(rb+j)*136 + feat] = f2bf(e);
    }
  }
  __syncthreads();   // kvT staged (vmcnt drained by barrier); P pass-1 visible
  f32x4 nc[4] = {};
  #pragma unroll
  for (int ks2=0; ks2<4; ++ks2){   // PV over features 0..127
    int kb = (ks2*32 + ((lane>>4)<<3))*2;
    int n = w*16 + (lane&15);
    short8 bfr = lds_read8(bufB, n*272 + kb);
    #pragma unroll
    for (int i=0;i<4;++i){
      int m = i*16 + (lane&15);
      short8 a = lds_read8(bufA, m*512 + kb);
      nc[i] = mfma16(a, bfr, nc[i]);
    }
  }
  #pragma unroll
  for (int ft=8;ft<16;++ft){  // pass 2: features 128..255 overwrite same wave-private rows
    int feat = ft*16 + (lane&15);
    float ksf = lKs[feat];
    #pragma unroll
    for (int j=0;j<4;++j){
      float e = __expf(p[ft][j]-sqv[j]-mj[j])*INVSQM + EPS_;
      dpart[j] += e*ksf;
      bufB[(rb+j)*136 + (feat-128)] = f2bf(e);
    }
  }
  #pragma unroll
  for (int j=0;j<4;++j){
    float v = dpart[j];
    v += __shfl_xor(v,1,64); v += __shfl_xor(v,2,64);
    v += __shfl_xor(v,4,64); v += __shfl_xor(v,8,64);
    if ((lane&15)==0) lDen[rb + j] = v;
  }
  #pragma unroll
  for (int ks2=4; ks2<8; ++ks2){   // PV over features 128..255
    int kbt = (ks2*32 + ((lane>>4)<<3))*2;
    int n = w*16 + (lane&15);
    short8 bfr = lds_read8(bufB, n*272 + (kbt - 256));
    #pragma unroll
    for (int i=0;i<4;++i){
      int m = i*16 + (lane&15);
      short8 a = lds_read8(bufA, m*512 + kbt);
      nc[i] = mfma16(a, bfr, nc[i]);
    }
  }
  const int b = bh >> 3, h = bh & 7;
  const int l = w*16 + (lane&15);
  float rden = 1.0f / (lDen[l] + EPS_);
  #pragma unroll
  for (int i=0;i<4;++i){
    short4v ov;
    #pragma unroll
    for (int jj=0;jj<4;++jj) ov[jj] = f2bf(nc[i][jj]*rden);
    size_t off = ((size_t)(b*L_ + l0 + l))*DM + h*DK + i*16 + ((lane>>4)<<2);
    *reinterpret_cast<short4v*>(attn + off) = ov;
  }
}

extern "C" void kernel_launch(void* const* d_in, const int* in_sizes, int n_in,
                              void* d_out, int out_size, void* d_ws, size_t ws_size,
                              hipStream_t stream){
  const float* Q  = (const float*)d_in[0];
  const float* K  = (const float*)d_in[1];
  const float* V  = (const float*)d_in[2];
  const float* Wq = (const float*)d_in[3];
  const float* Wk = (const float*)d_in[4];
  const float* Wv = (const float*)d_in[5];
  const float* Wo = (const float*)d_in[6];
  const float* Om = (const float*)d_in[7];
  char* ws = (char*)d_ws;

  short* wt  = (short*)(ws);                  // 2 MB (4 transposed 512x512 bf16)
  short* omc = (short*)(ws + 2097152);        // 64 KB slot

  k_wt<<<256, 256, 0, stream>>>(Wq, Wk, Wv, Wo, wt);
  k_omc<<<16, 256, 0, stream>>>(Om, omc);

  const size_t MONO_NEED = 120946688ull;      // ~115.3 MB
  if (ws_size >= MONO_NEED){
    short* qh   = (short*)(ws + 2162688);
    short* kh   = (short*)(ws + 35717120);
    short* vT   = (short*)(ws + 69271552);
    float* kvp  = (float*)(ws + 102825984);
    float* ksp  = (float*)(ws + 119603200);
    short* kvb  = (short*)(ws + 119865344);
    float* ksum = (float*)(ws + 120913920);
    short* attn = kh;                         // kh dead after k_phik
    k_gemm<0,true ><<<1024, 256, 0, stream>>>(Q, wt,          qh, 0);
    k_gemm<0,true ><<<1024, 256, 0, stream>>>(K, wt + 262144, kh, 0);
    k_gemm<2,true ><<<1024, 256, 0, stream>>>(V, wt + 524288, vT, 0);
    k_phik<<<256, 512, 0, stream>>>(kh, vT, omc, kvp, ksp);
    k_red<<<256, 256, 0, stream>>>(kvp, ksp, kvb, ksum);
    k_phiq<<<2048, 512, 0, stream>>>(qh, kvb, ksum, omc, attn);
    k_gemm<1,false><<<1024, 256, 0, stream>>>(attn, wt + 786432, d_out, 0);
  } else {
    // per-batch tier: ~30.4 MB of workspace
    short* qh   = (short*)(ws + 2162688);
    short* kh   = (short*)(ws + 10551296);
    short* vT   = (short*)(ws + 18939904);
    float* kvp  = (float*)(ws + 27328512);
    float* ksp  = (float*)(ws + 31522816);
    short* kvb  = (short*)(ws + 31588352);
    float* ksum = (float*)(ws + 31850496);
    short* attn = kh;
    for (int b=0; b<4; ++b){
      int rbase = b*8192;
      k_gemm<0,true ><<<256, 256, 0, stream>>>(Q, wt,          qh, rbase);
      k_gemm<0,true ><<<256, 256, 0, stream>>>(K, wt + 262144, kh, rbase);
      k_gemm<2,true ><<<256, 256, 0, stream>>>(V, wt + 524288, vT, rbase);
      k_phik<<<64, 512, 0, stream>>>(kh, vT, omc, kvp, ksp);
      k_red<<<64, 256, 0, stream>>>(kvp, ksp, kvb, ksum);
      k_phiq<<<512, 512, 0, stream>>>(qh, kvb, ksum, omc, attn);
      k_gemm<1,false><<<256, 256, 0, stream>>>(attn, wt + 786432,
                                               (float*)d_out + (size_t)b*8192*DM, 0);
    }
  }
}